// Round 14
// baseline (91.049 us; speedup 1.0000x reference)
//
#include <hip/hip_runtime.h>

#define N_PTS 20000
#define NA 20480            // candidates padded to 640 tiles of 32
#define NB 20032            // queries padded to 313 wave-groups of 64
#define TILES_TOTAL 640     // 32-candidate tiles
#define LCHUNK 5
#define NCHUNK 32           // 2^LCHUNK
#define TPC (TILES_TOTAL / NCHUNK)        // 20 tiles per chunk
#define CHUNK_BYTES (TPC * 1024)          // 20480 B per chunk (tile = 64 frags x 16B)
#define A_BYTES  (NA * 16 * 2)            // 655,360
#define B_BYTES  (NB * 16 * 2)            // 641,024
#define BEST_OFF (A_BYTES + B_BYTES)      // 1,296,384
#define CNT_OFF  (BEST_OFF + NB * 8)      // after u64 best[NB]

typedef __attribute__((ext_vector_type(8))) short bf16x8;
typedef __attribute__((ext_vector_type(16))) float f32x16;

static __device__ __forceinline__ unsigned short f2bf(float f) {
    unsigned int u = __float_as_uint(f);
    unsigned int r = (u + 0x7FFFu + ((u >> 16) & 1u)) >> 16;   // RNE
    return (unsigned short)r;
}
static __device__ __forceinline__ float bf2f(unsigned short h) {
    return __uint_as_float(((unsigned int)h) << 16);
}

// exact f32 key -> order-preserving u32, packed with index: min == (min key, then min idx)
static __device__ __forceinline__ unsigned long long packmin(float v, int idx) {
    unsigned u = __float_as_uint(v);
    u ^= (u & 0x80000000u) ? 0xFFFFFFFFu : 0x80000000u;
    return ((unsigned long long)u << 32) | (unsigned)idx;
}

// A row (candidate m), K=16 slots:
//   0-2: -2*c_hi (pairs q_hi) | 3-5: -2*c_hi (pairs q_lo) | 6-8: -2*c_lo (pairs q_hi)
//   9,10: y2 hi/lo (pair with 1.0); rest 0
// Amat layout is LANE-ORDERED per tile: fragment for MFMA-lane L of tile t lives at
//   byte offset t*1024 + L*16  (L=0..31: row L, k0..7; L=32..63: row L-31... i.e. row L&31, k8..15)
__global__ __launch_bounds__(256) void nn_prep(const float* __restrict__ q,
                                               const float* __restrict__ c,
                                               unsigned short* __restrict__ Amat,
                                               unsigned short* __restrict__ Bmat,
                                               unsigned long long* __restrict__ best,
                                               unsigned int* __restrict__ counters) {
    const int m = blockIdx.x * 256 + (int)threadIdx.x;
    if (m < 2) counters[m] = 0u;                  // ticket (+spare)
    if (m < NB) best[m] = 0xFFFFFFFFFFFFFFFFull;  // +max key
    if (m < NA) {
        unsigned short a[16];
        #pragma unroll
        for (int r = 0; r < 16; ++r) a[r] = 0;
        if (m < N_PTS) {
            const float cx = c[m * 3 + 0], cy = c[m * 3 + 1], cz = c[m * 3 + 2];
            const unsigned short hx = f2bf(cx), hy = f2bf(cy), hz = f2bf(cz);
            const float lx = cx - bf2f(hx), ly = cy - bf2f(hy), lz = cz - bf2f(hz);
            const float y2 = fmaf(cx, cx, fmaf(cy, cy, cz * cz));
            const unsigned short y2h = f2bf(y2);
            const unsigned short y2l = f2bf(y2 - bf2f(y2h));
            a[0] = f2bf(-2.f * bf2f(hx)); a[1] = f2bf(-2.f * bf2f(hy)); a[2] = f2bf(-2.f * bf2f(hz));
            a[3] = a[0]; a[4] = a[1]; a[5] = a[2];
            a[6] = f2bf(-2.f * lx); a[7] = f2bf(-2.f * ly); a[8] = f2bf(-2.f * lz);
            a[9] = y2h; a[10] = y2l;
        } else {
            a[9] = f2bf(1e30f);   // padded candidates: huge key, never wins
        }
        const int tile = m >> 5, l31 = m & 31;
        unsigned int* d0 = (unsigned int*)(Amat + (size_t)tile * 512 + l31 * 8);        // k0..7
        unsigned int* d1 = (unsigned int*)(Amat + (size_t)tile * 512 + 256 + l31 * 8);  // k8..15
        d0[0] = (unsigned)a[0] | ((unsigned)a[1] << 16);
        d0[1] = (unsigned)a[2] | ((unsigned)a[3] << 16);
        d0[2] = (unsigned)a[4] | ((unsigned)a[5] << 16);
        d0[3] = (unsigned)a[6] | ((unsigned)a[7] << 16);
        d1[0] = (unsigned)a[8] | ((unsigned)a[9] << 16);
        d1[1] = (unsigned)a[10] | ((unsigned)a[11] << 16);
        d1[2] = (unsigned)a[12] | ((unsigned)a[13] << 16);
        d1[3] = (unsigned)a[14] | ((unsigned)a[15] << 16);
    }
    if (m < NB) {
        unsigned short b[16];
        #pragma unroll
        for (int r = 0; r < 16; ++r) b[r] = 0;
        if (m < N_PTS) {
            const float qx = q[m * 3 + 0], qy = q[m * 3 + 1], qz = q[m * 3 + 2];
            const unsigned short hx = f2bf(qx), hy = f2bf(qy), hz = f2bf(qz);
            b[0] = hx; b[1] = hy; b[2] = hz;
            b[3] = f2bf(qx - bf2f(hx)); b[4] = f2bf(qy - bf2f(hy)); b[5] = f2bf(qz - bf2f(hz));
            b[6] = hx; b[7] = hy; b[8] = hz;
            b[9] = f2bf(1.0f); b[10] = f2bf(1.0f);
        }
        unsigned int* o = (unsigned int*)(Bmat + (size_t)m * 16);
        #pragma unroll
        for (int r = 0; r < 8; ++r)
            o[r] = (unsigned int)b[2 * r] | ((unsigned int)b[2 * r + 1] << 16);
    }
}

// min-tree over 16 accs: 7x v_min3 + 1x v_min (exact values)
static __device__ __forceinline__ float tree_min16(const f32x16& v) {
    const float t0 = fminf(fminf(v[0], v[1]), v[2]);
    const float t1 = fminf(fminf(v[3], v[4]), v[5]);
    const float t2 = fminf(fminf(v[6], v[7]), v[8]);
    const float t3 = fminf(fminf(v[9], v[10]), v[11]);
    const float t4 = fminf(fminf(v[12], v[13]), v[14]);
    const float t5 = fminf(fminf(t0, t1), v[15]);
    const float t6 = fminf(fminf(t2, t3), t4);
    return fminf(t5, t6);
}

// packed argmin over a tile's 16 regs: reg idx in low 4 bits (R3-proven)
static __device__ __forceinline__ int tile_argreg(const f32x16& v) {
    float pm = __uint_as_float(0x7F800000u);
    #pragma unroll
    for (int r = 0; r < 16; ++r)
        pm = fminf(pm, __uint_as_float((__float_as_uint(v[r]) & 0xFFFFFFF0u) | (unsigned)r));
    return (int)(__float_as_uint(pm) & 15u);
}

// Block = 4 waves sharing ONE candidate chunk STAGED IN LDS (20 KB -> 8 blocks/CU).
// Wave: 64 queries (2 B-frags of 32) x TPC=20 tiles; per tile 1 ds_read_b128 + 2 MFMA +
// {8-op exact min-tree + cmp/cndmask/min} per frag. Epilogue: recompute winning tile from
// LDS, packed argmin -> id; one atomicMin(u64) per lane. Last block (ticket) computes loss.
// 32x32x16 layouts (m74/m101, verified R3): C/D col=lane&31, row=(reg&3)+8*(reg>>2)+4*(lane>>5)
__global__ __launch_bounds__(256) void nn_main(const unsigned short* __restrict__ Amat,
                                               const unsigned short* __restrict__ Bmat,
                                               unsigned long long* __restrict__ best,
                                               const int* __restrict__ labels,
                                               unsigned int* __restrict__ ticket,
                                               float* __restrict__ out) {
    __shared__ __align__(16) unsigned short lds[TPC * 512];   // 20480 B
    __shared__ unsigned int bsum;
    __shared__ int islast;

    const int tid = (int)threadIdx.x;
    const int wav = tid >> 6;
    const int lane = tid & 63;
    const int l31 = lane & 31;
    const int half = lane >> 5;
    const int ch = (int)blockIdx.x & (NCHUNK - 1);
    const int qg = ((int)blockIdx.x >> LCHUNK) * 4 + wav;

    // cooperative stage: 20480 B = 1280 uint4, 256 threads x 5 iters (coalesced, linear)
    {
        const uint4* src = (const uint4*)((const char*)Amat + (size_t)ch * CHUNK_BYTES);
        uint4* dst = (uint4*)lds;
        #pragma unroll
        for (int it = 0; it < 5; ++it)
            dst[it * 256 + tid] = src[it * 256 + tid];
    }
    __syncthreads();

    if (qg < 313) {
        const int qbase = qg * 64;
        const bf16x8 b1 = *(const bf16x8*)(Bmat + (size_t)(qbase + l31) * 16 + half * 8);
        const bf16x8 b2 = *(const bf16x8*)(Bmat + (size_t)(qbase + 32 + l31) * 16 + half * 8);

        const f32x16 zacc = {0.f, 0.f, 0.f, 0.f, 0.f, 0.f, 0.f, 0.f,
                             0.f, 0.f, 0.f, 0.f, 0.f, 0.f, 0.f, 0.f};

        float bv1 = __uint_as_float(0x7F800000u), bv2 = bv1;   // +inf
        int bp1 = 0, bp2 = 0;

        #pragma unroll 2
        for (int t = 0; t < TPC; ++t) {
            const bf16x8 af = *(const bf16x8*)(lds + (size_t)t * 512 + lane * 8);  // conflict-free
            const f32x16 a1 = __builtin_amdgcn_mfma_f32_32x32x16_bf16(af, b1, zacc, 0, 0, 0);
            const f32x16 a2 = __builtin_amdgcn_mfma_f32_32x32x16_bf16(af, b2, zacc, 0, 0, 0);
            const float m1 = tree_min16(a1);
            if (m1 < bv1) bp1 = t;
            bv1 = fminf(bv1, m1);
            const float m2 = tree_min16(a2);
            if (m2 < bv2) bp2 = t;
            bv2 = fminf(bv2, m2);
        }

        // epilogue: recompute winning tile from LDS, packed argmin -> reg -> candidate id
        int bi1, bi2;
        {
            const bf16x8 e1 = *(const bf16x8*)(lds + (size_t)bp1 * 512 + lane * 8);
            const f32x16 r1 = __builtin_amdgcn_mfma_f32_32x32x16_bf16(e1, b1, zacc, 0, 0, 0);
            const int rg1 = tile_argreg(r1);
            bi1 = (ch * TPC + bp1) * 32 + (rg1 & 3) + 8 * (rg1 >> 2) + 4 * half;
            const bf16x8 e2 = *(const bf16x8*)(lds + (size_t)bp2 * 512 + lane * 8);
            const f32x16 r2 = __builtin_amdgcn_mfma_f32_32x32x16_bf16(e2, b2, zacc, 0, 0, 0);
            const int rg2 = tile_argreg(r2);
            bi2 = (ch * TPC + bp2) * 32 + (rg2 & 3) + 8 * (rg2 >> 2) + 4 * half;
        }

        // merge the two row-halves (lane ^ 32)
        const float ov1 = __shfl_xor(bv1, 32);
        const int oi1 = __shfl_xor(bi1, 32);
        if (ov1 < bv1 || (ov1 == bv1 && oi1 < bi1)) { bv1 = ov1; bi1 = oi1; }
        const float ov2 = __shfl_xor(bv2, 32);
        const int oi2 = __shfl_xor(bi2, 32);
        if (ov2 < bv2 || (ov2 == bv2 && oi2 < bi2)) { bv2 = ov2; bi2 = oi2; }

        // one atomic per lane: lanes 0-31 -> queries qbase+0..31 (frag1), 32-63 -> frag2
        const unsigned long long pk = half ? packmin(bv2, bi2) : packmin(bv1, bi1);
        atomicMin(&best[qbase + lane], pk);
    }

    __syncthreads();   // all waves' atomics issued
    if (tid == 0) {
        __threadfence();
        islast = (atomicAdd(ticket, 1u) == (unsigned)gridDim.x - 1u) ? 1 : 0;
        bsum = 0u;
    }
    __syncthreads();

    if (islast) {      // final reduction in the last-arriving block
        unsigned cnt = 0;
        for (int i = tid; i < N_PTS; i += 256) {
            const unsigned long long b =
                __hip_atomic_load(&best[i], __ATOMIC_RELAXED, __HIP_MEMORY_SCOPE_AGENT);
            int bidx = (int)(unsigned)(b & 0xFFFFFFFFull);
            bidx = (bidx < 0) ? 0 : ((bidx >= N_PTS) ? (N_PTS - 1) : bidx);   // fault guard
            cnt += (labels[bidx] != labels[i]) ? 1u : 0u;
        }
        #pragma unroll
        for (int off = 32; off > 0; off >>= 1) cnt += __shfl_down(cnt, off);
        if ((tid & 63) == 0) atomicAdd(&bsum, cnt);
        __syncthreads();
        if (tid == 0) out[0] = (float)bsum / (float)N_PTS;
    }
}

extern "C" void kernel_launch(void* const* d_in, const int* in_sizes, int n_in,
                              void* d_out, int out_size, void* d_ws, size_t ws_size,
                              hipStream_t stream) {
    const float* mean_3d      = (const float*)d_in[0];
    const float* mean_3d_cano = (const float*)d_in[1];
    const int*   segm_labels  = (const int*)d_in[2];
    float* out = (float*)d_out;

    unsigned short* Amat = (unsigned short*)d_ws;
    unsigned short* Bmat = (unsigned short*)((char*)d_ws + A_BYTES);
    unsigned long long* best = (unsigned long long*)((char*)d_ws + BEST_OFF);
    unsigned int* counters = (unsigned int*)((char*)d_ws + CNT_OFF);

    nn_prep<<<NA / 256, 256, 0, stream>>>(mean_3d, mean_3d_cano, Amat, Bmat, best, counters);
    nn_main<<<NCHUNK * 79, 256, 0, stream>>>(Amat, Bmat, best, segm_labels, counters, out);
}

// Round 15
// 37.832 us; speedup vs baseline: 2.4067x; 2.4067x over previous
//
#include <hip/hip_runtime.h>

#define N_PTS 20000
#define NA 20480            // candidates padded to 640 tiles of 32
#define NB 20032            // queries padded to 313 wave-groups of 64
#define TILES_TOTAL 640     // 32-candidate tiles
#define A_BYTES  (NA * 16 * 2)            // 655,360
#define B_BYTES  (NB * 16 * 2)            // 641,024
#define BEST_OFF (A_BYTES + B_BYTES)      // 1,296,384
#define CNT_OFF  (BEST_OFF + NB * 8)      // after u64 best[NB]

typedef __attribute__((ext_vector_type(8))) short bf16x8;
typedef __attribute__((ext_vector_type(16))) float f32x16;

static __device__ __forceinline__ unsigned short f2bf(float f) {
    unsigned int u = __float_as_uint(f);
    unsigned int r = (u + 0x7FFFu + ((u >> 16) & 1u)) >> 16;   // RNE
    return (unsigned short)r;
}
static __device__ __forceinline__ float bf2f(unsigned short h) {
    return __uint_as_float(((unsigned int)h) << 16);
}

// exact f32 key -> order-preserving u32, packed with index: min == (min key, then min idx)
static __device__ __forceinline__ unsigned long long packmin(float v, int idx) {
    unsigned u = __float_as_uint(v);
    u ^= (u & 0x80000000u) ? 0xFFFFFFFFu : 0x80000000u;
    return ((unsigned long long)u << 32) | (unsigned)idx;
}

// A row (candidate m), K=16 slots:
//   0-2: -2*c_hi (pairs q_hi) | 3-5: -2*c_hi (pairs q_lo) | 6-8: -2*c_lo (pairs q_hi)
//   9,10: y2 hi/lo (pair with 1.0); rest 0
// => acc ~= ||y||^2 - 2 x.y  (argmin key; x^2 constant per query)
__global__ __launch_bounds__(256) void nn_prep(const float* __restrict__ q,
                                               const float* __restrict__ c,
                                               unsigned short* __restrict__ Amat,
                                               unsigned short* __restrict__ Bmat,
                                               unsigned long long* __restrict__ best,
                                               unsigned int* __restrict__ counters) {
    const int m = blockIdx.x * 256 + (int)threadIdx.x;
    if (m < 2) counters[m] = 0u;                  // count + ticket
    if (m < NB) best[m] = 0xFFFFFFFFFFFFFFFFull;  // +max key
    if (m < NA) {
        unsigned short a[16];
        #pragma unroll
        for (int r = 0; r < 16; ++r) a[r] = 0;
        if (m < N_PTS) {
            const float cx = c[m * 3 + 0], cy = c[m * 3 + 1], cz = c[m * 3 + 2];
            const unsigned short hx = f2bf(cx), hy = f2bf(cy), hz = f2bf(cz);
            const float lx = cx - bf2f(hx), ly = cy - bf2f(hy), lz = cz - bf2f(hz);
            const float y2 = fmaf(cx, cx, fmaf(cy, cy, cz * cz));
            const unsigned short y2h = f2bf(y2);
            const unsigned short y2l = f2bf(y2 - bf2f(y2h));
            a[0] = f2bf(-2.f * bf2f(hx)); a[1] = f2bf(-2.f * bf2f(hy)); a[2] = f2bf(-2.f * bf2f(hz));
            a[3] = a[0]; a[4] = a[1]; a[5] = a[2];
            a[6] = f2bf(-2.f * lx); a[7] = f2bf(-2.f * ly); a[8] = f2bf(-2.f * lz);
            a[9] = y2h; a[10] = y2l;
        } else {
            a[9] = f2bf(1e30f);   // padded candidates: huge key, never wins
        }
        unsigned int* o = (unsigned int*)(Amat + (size_t)m * 16);
        #pragma unroll
        for (int r = 0; r < 8; ++r)
            o[r] = (unsigned int)a[2 * r] | ((unsigned int)a[2 * r + 1] << 16);
    }
    if (m < NB) {
        unsigned short b[16];
        #pragma unroll
        for (int r = 0; r < 16; ++r) b[r] = 0;
        if (m < N_PTS) {
            const float qx = q[m * 3 + 0], qy = q[m * 3 + 1], qz = q[m * 3 + 2];
            const unsigned short hx = f2bf(qx), hy = f2bf(qy), hz = f2bf(qz);
            b[0] = hx; b[1] = hy; b[2] = hz;
            b[3] = f2bf(qx - bf2f(hx)); b[4] = f2bf(qy - bf2f(hy)); b[5] = f2bf(qz - bf2f(hz));
            b[6] = hx; b[7] = hy; b[8] = hz;
            b[9] = f2bf(1.0f); b[10] = f2bf(1.0f);
        }
        unsigned int* o = (unsigned int*)(Bmat + (size_t)m * 16);
        #pragma unroll
        for (int r = 0; r < 8; ++r)
            o[r] = (unsigned int)b[2 * r] | ((unsigned int)b[2 * r + 1] << 16);
    }
}

// min-tree over 16 accs: 7x v_min3 + 1x v_min (exact values)
static __device__ __forceinline__ float tree_min16(const f32x16& v) {
    const float t0 = fminf(fminf(v[0], v[1]), v[2]);
    const float t1 = fminf(fminf(v[3], v[4]), v[5]);
    const float t2 = fminf(fminf(v[6], v[7]), v[8]);
    const float t3 = fminf(fminf(v[9], v[10]), v[11]);
    const float t4 = fminf(fminf(v[12], v[13]), v[14]);
    const float t5 = fminf(fminf(t0, t1), v[15]);
    const float t6 = fminf(fminf(t2, t3), t4);
    return fminf(t5, t6);
}

// packed argmin over a tile's 16 regs: reg idx in low 4 bits (R3-proven), no equality test
static __device__ __forceinline__ int tile_argreg(const f32x16& v) {
    float pm = __uint_as_float(0x7F800000u);
    #pragma unroll
    for (int r = 0; r < 16; ++r)
        pm = fminf(pm, __uint_as_float((__float_as_uint(v[r]) & 0xFFFFFFF0u) | (unsigned)r));
    return (int)(__float_as_uint(pm) & 15u);
}

// Block = 4 waves sharing ONE candidate chunk, different query groups.
// Wave: 64 queries (2 B-frags of 32) x TPC=20 tiles of 32 candidates.
// DEPTH-2 software pipeline: tile t+2's load issues while tile t computes -> L2 latency
// (~300cyc) hidden under ~2 iterations of compute. unroll 1 forbids hoisting (R8 lesson).
// Tail over-read (<=1KB past chunk) lands in Bmat region of d_ws: mapped, never used.
// In-loop per tile: 2 MFMA + {8-op exact min-tree + cmp/cndmask/min} per frag.
// Epilogue: recompute winning tile, packed argmin -> id; one atomicMin(u64) per lane.
// 32x32x16 layouts (m74/m101, verified R3): C/D col=lane&31, row=(reg&3)+8*(reg>>2)+4*(lane>>5)
template<int LC>
__global__ __launch_bounds__(256) void nn_main(const unsigned short* __restrict__ Amat,
                                               const unsigned short* __restrict__ Bmat,
                                               unsigned long long* __restrict__ best) {
    constexpr int C = 1 << LC;
    constexpr int TPC = TILES_TOTAL >> LC;

    const int wav = (int)(threadIdx.x >> 6);
    const int ch = blockIdx.x & (C - 1);
    const int qg = ((int)blockIdx.x >> LC) * 4 + wav;
    if (qg >= 313) return;
    const int lane = (int)(threadIdx.x & 63);
    const int qbase = qg * 64;
    const int l31 = lane & 31;
    const int half = lane >> 5;

    const bf16x8 b1 = *(const bf16x8*)(Bmat + (size_t)(qbase + l31) * 16 + half * 8);
    const bf16x8 b2 = *(const bf16x8*)(Bmat + (size_t)(qbase + 32 + l31) * 16 + half * 8);

    const f32x16 zacc = {0.f, 0.f, 0.f, 0.f, 0.f, 0.f, 0.f, 0.f,
                         0.f, 0.f, 0.f, 0.f, 0.f, 0.f, 0.f, 0.f};

    float bv1 = __uint_as_float(0x7F800000u), bv2 = bv1;   // +inf
    int bp1 = 0, bp2 = 0;

    const unsigned short* Abase = Amat + ((size_t)(ch * TPC) * 32 + l31) * 16 + half * 8;
    // depth-2 pipeline: af0 = tile t, af1 = tile t+1 in regs; load t+2 each iter
    bf16x8 af0 = *(const bf16x8*)Abase;
    bf16x8 af1 = *(const bf16x8*)(Abase + 512);
    #pragma unroll 1
    for (int t = 0; t < TPC; ++t) {
        const bf16x8 afn = *(const bf16x8*)(Abase + (size_t)(t + 2) * 512);  // prefetch t+2
        const f32x16 a1 = __builtin_amdgcn_mfma_f32_32x32x16_bf16(af0, b1, zacc, 0, 0, 0);
        const f32x16 a2 = __builtin_amdgcn_mfma_f32_32x32x16_bf16(af0, b2, zacc, 0, 0, 0);
        const float m1 = tree_min16(a1);
        if (m1 < bv1) bp1 = t;            // strict < : first tile attaining final min
        bv1 = fminf(bv1, m1);
        const float m2 = tree_min16(a2);
        if (m2 < bv2) bp2 = t;
        bv2 = fminf(bv2, m2);
        af0 = af1;
        af1 = afn;
    }

    // epilogue: recompute the winning tile, packed argmin -> reg -> candidate id
    int bi1, bi2;
    {
        const bf16x8 e1 = *(const bf16x8*)(Abase + (size_t)bp1 * 512);
        const f32x16 r1 = __builtin_amdgcn_mfma_f32_32x32x16_bf16(e1, b1, zacc, 0, 0, 0);
        const int rg1 = tile_argreg(r1);
        bi1 = (ch * TPC + bp1) * 32 + (rg1 & 3) + 8 * (rg1 >> 2) + 4 * half;
        const bf16x8 e2 = *(const bf16x8*)(Abase + (size_t)bp2 * 512);
        const f32x16 r2 = __builtin_amdgcn_mfma_f32_32x32x16_bf16(e2, b2, zacc, 0, 0, 0);
        const int rg2 = tile_argreg(r2);
        bi2 = (ch * TPC + bp2) * 32 + (rg2 & 3) + 8 * (rg2 >> 2) + 4 * half;
    }

    // merge the two row-halves (lane ^ 32); queries are col=lane&31, same in both halves
    const float ov1 = __shfl_xor(bv1, 32);
    const int oi1 = __shfl_xor(bi1, 32);
    if (ov1 < bv1 || (ov1 == bv1 && oi1 < bi1)) { bv1 = ov1; bi1 = oi1; }
    const float ov2 = __shfl_xor(bv2, 32);
    const int oi2 = __shfl_xor(bi2, 32);
    if (ov2 < bv2 || (ov2 == bv2 && oi2 < bi2)) { bv2 = ov2; bi2 = oi2; }

    // one atomic per lane: lanes 0-31 carry frag1 (queries qbase+0..31),
    // lanes 32-63 carry frag2 for queries qbase+32..63 (= qbase+lane)
    const unsigned long long pk = half ? packmin(bv2, bi2) : packmin(bv1, bi1);
    atomicMin(&best[qbase + lane], pk);
}

// Final: one load per query, count mismatches, last block writes the loss.
__global__ __launch_bounds__(256) void nn_final(const unsigned long long* __restrict__ best,
                                                const int* __restrict__ labels,
                                                unsigned int* __restrict__ count,
                                                unsigned int* __restrict__ ticket,
                                                float* __restrict__ out) {
    const int i = blockIdx.x * 256 + (int)threadIdx.x;
    int mism = 0;
    if (i < N_PTS) {
        int bidx = (int)(unsigned)(best[i] & 0xFFFFFFFFull);
        bidx = (bidx < 0) ? 0 : ((bidx >= N_PTS) ? (N_PTS - 1) : bidx);   // fault guard
        mism = (labels[bidx] != labels[i]) ? 1 : 0;
    }
    const unsigned long long msk = __ballot(mism != 0);
    __shared__ unsigned int bsum;
    if (threadIdx.x == 0) bsum = 0;
    __syncthreads();
    if ((threadIdx.x & 63) == 0) atomicAdd(&bsum, (unsigned)__popcll(msk));
    __syncthreads();
    if (threadIdx.x == 0) {
        atomicAdd(count, bsum);
        __threadfence();
        const unsigned t = atomicAdd(ticket, 1u);
        if (t == gridDim.x - 1) {
            __threadfence();
            const unsigned total = atomicAdd(count, 0u);
            out[0] = (float)total / (float)N_PTS;
        }
    }
}

extern "C" void kernel_launch(void* const* d_in, const int* in_sizes, int n_in,
                              void* d_out, int out_size, void* d_ws, size_t ws_size,
                              hipStream_t stream) {
    const float* mean_3d      = (const float*)d_in[0];
    const float* mean_3d_cano = (const float*)d_in[1];
    const int*   segm_labels  = (const int*)d_in[2];
    float* out = (float*)d_out;

    unsigned short* Amat = (unsigned short*)d_ws;
    unsigned short* Bmat = (unsigned short*)((char*)d_ws + A_BYTES);
    unsigned long long* best = (unsigned long long*)((char*)d_ws + BEST_OFF);
    unsigned int* counters = (unsigned int*)((char*)d_ws + CNT_OFF);

    constexpr int lc = 5;                                   // 32 chunks (TPC=20)
    constexpr int C = 1 << lc;

    nn_prep<<<NA / 256, 256, 0, stream>>>(mean_3d, mean_3d_cano, Amat, Bmat, best, counters);
    nn_main<lc><<<C * 79, 256, 0, stream>>>(Amat, Bmat, best);
    nn_final<<<(N_PTS + 255) / 256, 256, 0, stream>>>(best, segm_labels, counters, counters + 1, out);
}

// Round 16
// 31.781 us; speedup vs baseline: 2.8649x; 1.1904x over previous
//
#include <hip/hip_runtime.h>

#define N_PTS 20000
#define NA 20480            // candidates padded to 640 tiles of 32
#define NB 20032            // queries padded to 313 wave-groups of 64
#define TILES_TOTAL 640     // 32-candidate tiles
#define A_BYTES  (NA * 16 * 2)            // 655,360
#define B_BYTES  (NB * 16 * 2)            // 641,024
#define BEST_OFF (A_BYTES + B_BYTES)      // 1,296,384
#define CNT_OFF  (BEST_OFF + NB * 8)      // after u64 best[NB]

typedef __attribute__((ext_vector_type(8))) short bf16x8;
typedef __attribute__((ext_vector_type(16))) float f32x16;

static __device__ __forceinline__ unsigned short f2bf(float f) {
    unsigned int u = __float_as_uint(f);
    unsigned int r = (u + 0x7FFFu + ((u >> 16) & 1u)) >> 16;   // RNE
    return (unsigned short)r;
}
static __device__ __forceinline__ float bf2f(unsigned short h) {
    return __uint_as_float(((unsigned int)h) << 16);
}

// exact f32 key -> order-preserving u32, packed with index: min == (min key, then min idx)
static __device__ __forceinline__ unsigned long long packmin(float v, int idx) {
    unsigned u = __float_as_uint(v);
    u ^= (u & 0x80000000u) ? 0xFFFFFFFFu : 0x80000000u;
    return ((unsigned long long)u << 32) | (unsigned)idx;
}

// A row (candidate m), K=16 slots:
//   0-2: -2*c_hi (pairs q_hi) | 3-5: -2*c_hi (pairs q_lo) | 6-8: -2*c_lo (pairs q_hi)
//   9,10: y2 hi/lo (pair with 1.0); rest 0
// => acc ~= ||y||^2 - 2 x.y  (argmin key; x^2 constant per query)
__global__ __launch_bounds__(256) void nn_prep(const float* __restrict__ q,
                                               const float* __restrict__ c,
                                               unsigned short* __restrict__ Amat,
                                               unsigned short* __restrict__ Bmat,
                                               unsigned long long* __restrict__ best,
                                               unsigned int* __restrict__ counters) {
    const int m = blockIdx.x * 256 + (int)threadIdx.x;
    if (m < 2) counters[m] = 0u;                  // count + ticket
    if (m < NB) best[m] = 0xFFFFFFFFFFFFFFFFull;  // +max key
    if (m < NA) {
        unsigned short a[16];
        #pragma unroll
        for (int r = 0; r < 16; ++r) a[r] = 0;
        if (m < N_PTS) {
            const float cx = c[m * 3 + 0], cy = c[m * 3 + 1], cz = c[m * 3 + 2];
            const unsigned short hx = f2bf(cx), hy = f2bf(cy), hz = f2bf(cz);
            const float lx = cx - bf2f(hx), ly = cy - bf2f(hy), lz = cz - bf2f(hz);
            const float y2 = fmaf(cx, cx, fmaf(cy, cy, cz * cz));
            const unsigned short y2h = f2bf(y2);
            const unsigned short y2l = f2bf(y2 - bf2f(y2h));
            a[0] = f2bf(-2.f * bf2f(hx)); a[1] = f2bf(-2.f * bf2f(hy)); a[2] = f2bf(-2.f * bf2f(hz));
            a[3] = a[0]; a[4] = a[1]; a[5] = a[2];
            a[6] = f2bf(-2.f * lx); a[7] = f2bf(-2.f * ly); a[8] = f2bf(-2.f * lz);
            a[9] = y2h; a[10] = y2l;
        } else {
            a[9] = f2bf(1e30f);   // padded candidates: huge key, never wins
        }
        unsigned int* o = (unsigned int*)(Amat + (size_t)m * 16);
        #pragma unroll
        for (int r = 0; r < 8; ++r)
            o[r] = (unsigned int)a[2 * r] | ((unsigned int)a[2 * r + 1] << 16);
    }
    if (m < NB) {
        unsigned short b[16];
        #pragma unroll
        for (int r = 0; r < 16; ++r) b[r] = 0;
        if (m < N_PTS) {
            const float qx = q[m * 3 + 0], qy = q[m * 3 + 1], qz = q[m * 3 + 2];
            const unsigned short hx = f2bf(qx), hy = f2bf(qy), hz = f2bf(qz);
            b[0] = hx; b[1] = hy; b[2] = hz;
            b[3] = f2bf(qx - bf2f(hx)); b[4] = f2bf(qy - bf2f(hy)); b[5] = f2bf(qz - bf2f(hz));
            b[6] = hx; b[7] = hy; b[8] = hz;
            b[9] = f2bf(1.0f); b[10] = f2bf(1.0f);
        }
        unsigned int* o = (unsigned int*)(Bmat + (size_t)m * 16);
        #pragma unroll
        for (int r = 0; r < 8; ++r)
            o[r] = (unsigned int)b[2 * r] | ((unsigned int)b[2 * r + 1] << 16);
    }
}

// min-tree over 16 accs: 7x v_min3 + 1x v_min (exact values)
static __device__ __forceinline__ float tree_min16(const f32x16& v) {
    const float t0 = fminf(fminf(v[0], v[1]), v[2]);
    const float t1 = fminf(fminf(v[3], v[4]), v[5]);
    const float t2 = fminf(fminf(v[6], v[7]), v[8]);
    const float t3 = fminf(fminf(v[9], v[10]), v[11]);
    const float t4 = fminf(fminf(v[12], v[13]), v[14]);
    const float t5 = fminf(fminf(t0, t1), v[15]);
    const float t6 = fminf(fminf(t2, t3), t4);
    return fminf(t5, t6);
}

// packed argmin over a tile's 16 regs: reg idx in low 4 bits (R3-proven), no equality test
static __device__ __forceinline__ int tile_argreg(const f32x16& v) {
    float pm = __uint_as_float(0x7F800000u);
    #pragma unroll
    for (int r = 0; r < 16; ++r)
        pm = fminf(pm, __uint_as_float((__float_as_uint(v[r]) & 0xFFFFFFF0u) | (unsigned)r));
    return (int)(__float_as_uint(pm) & 15u);
}

// Block = 4 waves sharing ONE candidate chunk, different query groups.
// Wave: 64 queries (2 B-frags of 32) x TPC=20 tiles of 32 candidates.
// __launch_bounds__(256,2): 256-VGPR budget so MFMA accs live in arch VGPRs
// (plain (256) targets 8 waves/SIMD = 64-reg budget -> AGPR-form MFMA + accvgpr
// copy storms; the suspected cause of the persistent ~2x VALU inflation).
// Accs consumed one at a time (peak live acc = 16 regs).
// In-loop per tile: 2 MFMA + {8-op exact min-tree + cmp/cndmask/min} per frag.
// Epilogue: recompute winning tile, packed argmin -> id; one atomicMin(u64) per lane.
// 32x32x16 layouts (m74/m101, verified R3): C/D col=lane&31, row=(reg&3)+8*(reg>>2)+4*(lane>>5)
template<int LC>
__global__ __launch_bounds__(256, 2) void nn_main(const unsigned short* __restrict__ Amat,
                                                  const unsigned short* __restrict__ Bmat,
                                                  unsigned long long* __restrict__ best) {
    constexpr int C = 1 << LC;
    constexpr int TPC = TILES_TOTAL >> LC;

    const int wav = (int)(threadIdx.x >> 6);
    const int ch = blockIdx.x & (C - 1);
    const int qg = ((int)blockIdx.x >> LC) * 4 + wav;
    if (qg >= 313) return;
    const int lane = (int)(threadIdx.x & 63);
    const int qbase = qg * 64;
    const int l31 = lane & 31;
    const int half = lane >> 5;

    const bf16x8 b1 = *(const bf16x8*)(Bmat + (size_t)(qbase + l31) * 16 + half * 8);
    const bf16x8 b2 = *(const bf16x8*)(Bmat + (size_t)(qbase + 32 + l31) * 16 + half * 8);

    const f32x16 zacc = {0.f, 0.f, 0.f, 0.f, 0.f, 0.f, 0.f, 0.f,
                         0.f, 0.f, 0.f, 0.f, 0.f, 0.f, 0.f, 0.f};

    float bv1 = __uint_as_float(0x7F800000u), bv2 = bv1;   // +inf
    int bp1 = 0, bp2 = 0;

    const unsigned short* Abase = Amat + ((size_t)(ch * TPC) * 32 + l31) * 16 + half * 8;
    const unsigned short* Ap = Abase;
    #pragma unroll 2
    for (int t = 0; t < TPC; ++t) {
        const bf16x8 af = *(const bf16x8*)Ap;
        Ap += 512;                        // 32 rows * 16 shorts
        const f32x16 a1 = __builtin_amdgcn_mfma_f32_32x32x16_bf16(af, b1, zacc, 0, 0, 0);
        const float m1 = tree_min16(a1);  // consume a1 before a2 exists (16 acc regs live)
        if (m1 < bv1) bp1 = t;            // strict < : first tile attaining final min
        bv1 = fminf(bv1, m1);
        const f32x16 a2 = __builtin_amdgcn_mfma_f32_32x32x16_bf16(af, b2, zacc, 0, 0, 0);
        const float m2 = tree_min16(a2);
        if (m2 < bv2) bp2 = t;
        bv2 = fminf(bv2, m2);
    }

    // epilogue: recompute the winning tile, packed argmin -> reg -> candidate id
    int bi1, bi2;
    {
        const bf16x8 e1 = *(const bf16x8*)(Abase + (size_t)bp1 * 512);
        const f32x16 r1 = __builtin_amdgcn_mfma_f32_32x32x16_bf16(e1, b1, zacc, 0, 0, 0);
        const int rg1 = tile_argreg(r1);
        bi1 = (ch * TPC + bp1) * 32 + (rg1 & 3) + 8 * (rg1 >> 2) + 4 * half;
        const bf16x8 e2 = *(const bf16x8*)(Abase + (size_t)bp2 * 512);
        const f32x16 r2 = __builtin_amdgcn_mfma_f32_32x32x16_bf16(e2, b2, zacc, 0, 0, 0);
        const int rg2 = tile_argreg(r2);
        bi2 = (ch * TPC + bp2) * 32 + (rg2 & 3) + 8 * (rg2 >> 2) + 4 * half;
    }

    // merge the two row-halves (lane ^ 32); queries are col=lane&31, same in both halves
    const float ov1 = __shfl_xor(bv1, 32);
    const int oi1 = __shfl_xor(bi1, 32);
    if (ov1 < bv1 || (ov1 == bv1 && oi1 < bi1)) { bv1 = ov1; bi1 = oi1; }
    const float ov2 = __shfl_xor(bv2, 32);
    const int oi2 = __shfl_xor(bi2, 32);
    if (ov2 < bv2 || (ov2 == bv2 && oi2 < bi2)) { bv2 = ov2; bi2 = oi2; }

    // one atomic per lane: lanes 0-31 carry frag1 (queries qbase+0..31),
    // lanes 32-63 carry frag2 for queries qbase+32..63 (= qbase+lane)
    const unsigned long long pk = half ? packmin(bv2, bi2) : packmin(bv1, bi1);
    atomicMin(&best[qbase + lane], pk);
}

// Final: one load per query, count mismatches, last block writes the loss.
__global__ __launch_bounds__(256) void nn_final(const unsigned long long* __restrict__ best,
                                                const int* __restrict__ labels,
                                                unsigned int* __restrict__ count,
                                                unsigned int* __restrict__ ticket,
                                                float* __restrict__ out) {
    const int i = blockIdx.x * 256 + (int)threadIdx.x;
    int mism = 0;
    if (i < N_PTS) {
        int bidx = (int)(unsigned)(best[i] & 0xFFFFFFFFull);
        bidx = (bidx < 0) ? 0 : ((bidx >= N_PTS) ? (N_PTS - 1) : bidx);   // fault guard
        mism = (labels[bidx] != labels[i]) ? 1 : 0;
    }
    const unsigned long long msk = __ballot(mism != 0);
    __shared__ unsigned int bsum;
    if (threadIdx.x == 0) bsum = 0;
    __syncthreads();
    if ((threadIdx.x & 63) == 0) atomicAdd(&bsum, (unsigned)__popcll(msk));
    __syncthreads();
    if (threadIdx.x == 0) {
        atomicAdd(count, bsum);
        __threadfence();
        const unsigned t = atomicAdd(ticket, 1u);
        if (t == gridDim.x - 1) {
            __threadfence();
            const unsigned total = atomicAdd(count, 0u);
            out[0] = (float)total / (float)N_PTS;
        }
    }
}

extern "C" void kernel_launch(void* const* d_in, const int* in_sizes, int n_in,
                              void* d_out, int out_size, void* d_ws, size_t ws_size,
                              hipStream_t stream) {
    const float* mean_3d      = (const float*)d_in[0];
    const float* mean_3d_cano = (const float*)d_in[1];
    const int*   segm_labels  = (const int*)d_in[2];
    float* out = (float*)d_out;

    unsigned short* Amat = (unsigned short*)d_ws;
    unsigned short* Bmat = (unsigned short*)((char*)d_ws + A_BYTES);
    unsigned long long* best = (unsigned long long*)((char*)d_ws + BEST_OFF);
    unsigned int* counters = (unsigned int*)((char*)d_ws + CNT_OFF);

    constexpr int lc = 5;                                   // 32 chunks (TPC=20)
    constexpr int C = 1 << lc;

    nn_prep<<<NA / 256, 256, 0, stream>>>(mean_3d, mean_3d_cano, Amat, Bmat, best, counters);
    nn_main<lc><<<C * 79, 256, 0, stream>>>(Amat, Bmat, best);
    nn_final<<<(N_PTS + 255) / 256, 256, 0, stream>>>(best, segm_labels, counters, counters + 1, out);
}